// Round 6
// baseline (1128.278 us; speedup 1.0000x reference)
//
#include <hip/hip_runtime.h>
#include <hip/hip_bf16.h>

using f32x4  = __attribute__((ext_vector_type(4))) float;
using bf16x8 = __attribute__((ext_vector_type(8))) short;
using short8 = __attribute__((ext_vector_type(8))) short;
using s16x4  = __attribute__((ext_vector_type(4))) short;

#define DEVINL __device__ __forceinline__

DEVINL short f2bf(float f) {
  unsigned u = __builtin_bit_cast(unsigned, f);
  u += 0x7fffu + ((u >> 16) & 1u);          // RNE
  return (short)(u >> 16);
}

#define GLDS16(g, l) __builtin_amdgcn_global_load_lds( \
    (const __attribute__((address_space(1))) void*)(g), \
    (__attribute__((address_space(3))) void*)(l), 16, 0, 0)

// ---------------------------------------------------------------- transpose
// out[c*R + r] = in[r*C + c]  (fp32 -> bf16), builds B^T weight layouts
__global__ __launch_bounds__(256)
void transpose_bf16(const float* __restrict__ in, short* __restrict__ out, int R, int C) {
  int idx = blockIdx.x * 256 + threadIdx.x;
  if (idx >= R * C) return;
  int c = idx / R, r = idx % R;
  out[idx] = f2bf(in[(size_t)r * C + c]);
}

// ---------------------------------------------------------------- bias expand
// BIASF[head][n][m] = rpb[rpi(n,m)][head]   (16x64x64 f32 = 256KB, L2-hot)
__global__ __launch_bounds__(256)
void bias_expand(const float* __restrict__ rpb, float* __restrict__ BIASF) {
  int idx = blockIdx.x * 256 + threadIdx.x;   // 65536
  int head = idx >> 12, n = (idx >> 6) & 63, m = idx & 63;
  int i1 = n >> 3, j1 = n & 7, i2 = m >> 3, j2 = m & 7;
  BIASF[idx] = rpb[((i1 - i2 + 7) * 15 + (j1 - j2 + 7)) * 16 + head];
}

// ---------------------------------------------------------------- LayerNorm
// one wave per token (64 lanes x 8 ch = 512). REMAP=1: shift+window-partition dest.
template<int REMAP>
__global__ __launch_bounds__(256)
void ln_kernel(const float* __restrict__ X, const float* __restrict__ gamma,
               const float* __restrict__ beta, short* __restrict__ OUT) {
  const int lane = threadIdx.x & 63;
  const int wid  = threadIdx.x >> 6;
  const int t    = blockIdx.x * 4 + wid;
  const float* xp = X + (size_t)t * 512 + lane * 8;
  float4 a = *(const float4*)xp;
  float4 b = *(const float4*)(xp + 4);
  float s = a.x + a.y + a.z + a.w + b.x + b.y + b.z + b.w;
  float q = a.x*a.x + a.y*a.y + a.z*a.z + a.w*a.w
          + b.x*b.x + b.y*b.y + b.z*b.z + b.w*b.w;
#pragma unroll
  for (int d = 1; d < 64; d <<= 1) { s += __shfl_xor(s, d); q += __shfl_xor(q, d); }
  float mean = s * (1.0f / 512.0f);
  float var  = q * (1.0f / 512.0f) - mean * mean;
  float rstd = rsqrtf(var + 1e-5f);
  float4 g0 = *(const float4*)(gamma + lane * 8);
  float4 g1 = *(const float4*)(gamma + lane * 8 + 4);
  float4 b0 = *(const float4*)(beta + lane * 8);
  float4 b1 = *(const float4*)(beta + lane * 8 + 4);
  short8 o;
  o[0] = f2bf((a.x - mean) * rstd * g0.x + b0.x);
  o[1] = f2bf((a.y - mean) * rstd * g0.y + b0.y);
  o[2] = f2bf((a.z - mean) * rstd * g0.z + b0.z);
  o[3] = f2bf((a.w - mean) * rstd * g0.w + b0.w);
  o[4] = f2bf((b.x - mean) * rstd * g1.x + b1.x);
  o[5] = f2bf((b.y - mean) * rstd * g1.y + b1.y);
  o[6] = f2bf((b.z - mean) * rstd * g1.z + b1.z);
  o[7] = f2bf((b.w - mean) * rstd * g1.w + b1.w);
  size_t orow;
  if (REMAP) {
    int bb = t >> 12, l = t & 4095, hh = l >> 6, ww = l & 63;
    int hs = (hh + 60) & 63, ws2 = (ww + 60) & 63;   // (coord - 4) mod 64
    orow = (size_t)(bb * 64 + (hs >> 3) * 8 + (ws2 >> 3)) * 64 + (hs & 7) * 8 + (ws2 & 7);
  } else {
    orow = (size_t)t;
  }
  *(short8*)(OUT + orow * 512 + lane * 8) = o;
}

// ---------------------------------------------------------------- attention core
// one wave = one (window, head). LDS: per-wave P[64][64] bf16, XOR-swizzled.
__global__ __launch_bounds__(256)
void attn_core(const short* __restrict__ Q, const short* __restrict__ Kb,
               const short* __restrict__ VT, const float* __restrict__ BIASF,
               short* __restrict__ AOUT) {
  __shared__ short P[4][4096];
  const int tid = threadIdx.x, lane = tid & 63, wid = tid >> 6;
  const int lr = lane & 15, lg = lane >> 4;
  const int gw = blockIdx.x * 4 + wid;
  const int win = gw >> 4, head = gw & 15;
  const int wimg = win & 63, wh = wimg >> 3, ww = wimg & 7;
  const size_t qbase = (size_t)win * 64 * 512 + head * 32;
  short* Pb = P[wid];

  // ---- S = q k^T (scale pre-folded into Q)
  bf16x8 aq[4], bk[4];
#pragma unroll
  for (int tm = 0; tm < 4; ++tm) aq[tm] = *(const bf16x8*)(Q  + qbase + (size_t)(tm * 16 + lr) * 512 + lg * 8);
#pragma unroll
  for (int tn = 0; tn < 4; ++tn) bk[tn] = *(const bf16x8*)(Kb + qbase + (size_t)(tn * 16 + lr) * 512 + lg * 8);
  f32x4 sa[4][4] = {};
#pragma unroll
  for (int tm = 0; tm < 4; ++tm)
#pragma unroll
    for (int tn = 0; tn < 4; ++tn)
      sa[tm][tn] = __builtin_amdgcn_mfma_f32_16x16x32_bf16(aq[tm], bk[tn], sa[tm][tn], 0, 0, 0);

  // ---- softmax (rows n = tm*16+lg*4+e; cols m = tn*16+lr), 1/sum deferred
  const float* bias_h = BIASF + head * 4096;
  float inv[4][4];
#pragma unroll
  for (int tm = 0; tm < 4; ++tm) {
#pragma unroll
    for (int e = 0; e < 4; ++e) {
      const int n = tm * 16 + lg * 4 + e;
      const int i1 = n >> 3, j1 = n & 7;
      const int rh1 = (wh == 7) ? 1 + (i1 >> 2) : 0;
      const int rw1 = (ww == 7) ? 1 + (j1 >> 2) : 0;
      float v[4];
      float mx = -3.0e38f;
#pragma unroll
      for (int tn = 0; tn < 4; ++tn) {
        const int m = tn * 16 + lr;
        const int mi = (m >> 3), mj = m & 7;
        const int rh2 = (wh == 7) ? 1 + (mi >> 2) : 0;
        const int rw2 = (ww == 7) ? 1 + (mj >> 2) : 0;
        float val = sa[tm][tn][e] + bias_h[n * 64 + m]
                  + ((rh1 != rh2 || rw1 != rw2) ? -100.0f : 0.0f);
        v[tn] = val;
        mx = fmaxf(mx, val);
      }
#pragma unroll
      for (int d = 1; d < 16; d <<= 1) mx = fmaxf(mx, __shfl_xor(mx, d));
      float sum = 0.f;
#pragma unroll
      for (int tn = 0; tn < 4; ++tn) { v[tn] = __expf(v[tn] - mx); sum += v[tn]; }
#pragma unroll
      for (int d = 1; d < 16; d <<= 1) sum += __shfl_xor(sum, d);
      inv[tm][e] = 1.0f / sum;
      const int sw = (n & 7) << 3;
#pragma unroll
      for (int tn = 0; tn < 4; ++tn) Pb[n * 64 + ((tn * 16 + lr) ^ sw)] = f2bf(v[tn]);
    }
  }
  __syncthreads();

  // ---- O = P @ V  (B from VT[win][head][d][n], contiguous global loads)
  f32x4 oa[4][2] = {};
  const short* vt = VT + (size_t)win * 32768 + head * 2048;
#pragma unroll
  for (int ks = 0; ks < 2; ++ks) {
    bf16x8 pa[4], bv[2];
#pragma unroll
    for (int tm = 0; tm < 4; ++tm) {
      const int r = tm * 16 + lr;
      pa[tm] = *(const bf16x8*)(Pb + r * 64 + ((ks * 32 + lg * 8) ^ ((r & 7) << 3)));
    }
#pragma unroll
    for (int t2 = 0; t2 < 2; ++t2) bv[t2] = *(const bf16x8*)(vt + (t2 * 16 + lr) * 64 + ks * 32 + lg * 8);
#pragma unroll
    for (int tm = 0; tm < 4; ++tm)
#pragma unroll
      for (int t2 = 0; t2 < 2; ++t2)
        oa[tm][t2] = __builtin_amdgcn_mfma_f32_16x16x32_bf16(pa[tm], bv[t2], oa[tm][t2], 0, 0, 0);
  }
#pragma unroll
  for (int tm = 0; tm < 4; ++tm)
#pragma unroll
    for (int t2 = 0; t2 < 2; ++t2)
#pragma unroll
      for (int e = 0; e < 4; ++e) {
        const int n = tm * 16 + lg * 4 + e;
        AOUT[((size_t)win * 64 + n) * 512 + head * 32 + t2 * 16 + lr] = f2bf(oa[tm][t2][e] * inv[tm][e]);
      }
}

// ---------------------------------------------------------------- fused MLP v2
// out = X2 + fc2(gelu(fc1(ln(X2)))).  Block = 64 rows, 8 waves.
// fc1 operand-swapped: mfma(W1-frag, Xtok-frag) -> Ht[h][tok]; per-thread 4
// consecutive h => packed s16x4 writes into Hs[tok][128h] (^((tok&3)<<5)).
// Hs double-buffered => 1 barrier per hc chunk.
__global__ __launch_bounds__(512, 1)
void mlp_fused(const float* __restrict__ X2, const float* __restrict__ g2,
               const float* __restrict__ b2,
               const short* __restrict__ W1T, const float* __restrict__ fb1,
               const short* __restrict__ W2T, const float* __restrict__ fb2,
               float* __restrict__ out) {
  __shared__ short A[64 * 512];        // 64 KB, swz ^((tok&7)<<4)
  __shared__ short Hsb[2][64 * 128];   // 2 x 16 KB, swz ^((tok&3)<<5)
  const int tid = threadIdx.x, lane = tid & 63, w = tid >> 6;
  const int lr = lane & 15, lg = lane >> 4;
  const int m0 = blockIdx.x * 64;

  // ---- LN staging: wave w normalizes rows w*8 .. w*8+7 into A (swizzled)
  {
    float4 gg0 = *(const float4*)(g2 + lane * 8);
    float4 gg1 = *(const float4*)(g2 + lane * 8 + 4);
    float4 bb0 = *(const float4*)(b2 + lane * 8);
    float4 bb1 = *(const float4*)(b2 + lane * 8 + 4);
    for (int rr = 0; rr < 8; ++rr) {
      const int r = w * 8 + rr;
      const float* xp = X2 + (size_t)(m0 + r) * 512 + lane * 8;
      float4 a = *(const float4*)xp;
      float4 b = *(const float4*)(xp + 4);
      float s = a.x + a.y + a.z + a.w + b.x + b.y + b.z + b.w;
      float q = a.x*a.x + a.y*a.y + a.z*a.z + a.w*a.w
              + b.x*b.x + b.y*b.y + b.z*b.z + b.w*b.w;
#pragma unroll
      for (int d = 1; d < 64; d <<= 1) { s += __shfl_xor(s, d); q += __shfl_xor(q, d); }
      float mean = s * (1.0f / 512.0f);
      float var  = q * (1.0f / 512.0f) - mean * mean;
      float rstd = rsqrtf(var + 1e-5f);
      short8 o;
      o[0] = f2bf((a.x - mean) * rstd * gg0.x + bb0.x);
      o[1] = f2bf((a.y - mean) * rstd * gg0.y + bb0.y);
      o[2] = f2bf((a.z - mean) * rstd * gg0.z + bb0.z);
      o[3] = f2bf((a.w - mean) * rstd * gg0.w + bb0.w);
      o[4] = f2bf((b.x - mean) * rstd * gg1.x + bb1.x);
      o[5] = f2bf((b.y - mean) * rstd * gg1.y + bb1.y);
      o[6] = f2bf((b.z - mean) * rstd * gg1.z + bb1.z);
      o[7] = f2bf((b.w - mean) * rstd * gg1.w + bb1.w);
      *(short8*)((char*)A + ((r * 1024 + lane * 16) ^ ((r & 7) << 4))) = o;
    }
  }
  __syncthreads();   // A tile complete before any wave's fc1 reads cross-wave rows

  // fc1 for chunk hc into Hsb[hc&1]; h = hc*128 + w*16 + {lr rows}
  auto fc1_chunk = [&](int hc) {
    f32x4 ht[4] = {};
    const short* w1p = W1T + (size_t)(hc * 128 + w * 16 + lr) * 512 + lg * 8;
#pragma unroll
    for (int kk = 0; kk < 16; ++kk) {
      bf16x8 wfrag = *(const bf16x8*)(w1p + kk * 32);
      bf16x8 tfr[4];
#pragma unroll
      for (int tm = 0; tm < 4; ++tm) {
        const int tok = tm * 16 + lr;
        tfr[tm] = *(const bf16x8*)((const char*)A + ((tok * 1024 + kk * 64 + lg * 16) ^ ((tok & 7) << 4)));
      }
#pragma unroll
      for (int tm = 0; tm < 4; ++tm)
        ht[tm] = __builtin_amdgcn_mfma_f32_16x16x32_bf16(wfrag, tfr[tm], ht[tm], 0, 0, 0);
    }
    // C layout: row(h_local) = w*16 + lg*4 + e, col(tok) = tm*16 + lr.
    const float hb0 = fb1[hc * 128 + w * 16 + lg * 4 + 0];
    const float hb1 = fb1[hc * 128 + w * 16 + lg * 4 + 1];
    const float hb2 = fb1[hc * 128 + w * 16 + lg * 4 + 2];
    const float hb3 = fb1[hc * 128 + w * 16 + lg * 4 + 3];
    char* hsb = (char*)Hsb[hc & 1];
#pragma unroll
    for (int tm = 0; tm < 4; ++tm) {
      const int tok = tm * 16 + lr;
      float v0 = ht[tm][0] + hb0, v1 = ht[tm][1] + hb1;
      float v2 = ht[tm][2] + hb2, v3 = ht[tm][3] + hb3;
      s16x4 o;
      o[0] = f2bf(0.5f * v0 * (1.0f + erff(v0 * 0.70710678118654752f)));
      o[1] = f2bf(0.5f * v1 * (1.0f + erff(v1 * 0.70710678118654752f)));
      o[2] = f2bf(0.5f * v2 * (1.0f + erff(v2 * 0.70710678118654752f)));
      o[3] = f2bf(0.5f * v3 * (1.0f + erff(v3 * 0.70710678118654752f)));
      *(s16x4*)(hsb + ((tok * 256 + w * 32 + lg * 8) ^ ((tok & 3) << 5))) = o;
    }
  };

  f32x4 acc2[4][4] = {};           // 64 rows x 64 cols (w*64 ..)
  fc1_chunk(0);
  for (int hc = 0; hc < 16; ++hc) {
    __syncthreads();
    if (hc + 1 < 16) fc1_chunk(hc + 1);
    // ---- fc2 partial from Hsb[hc&1]: K = 128
    const char* hsb = (const char*)Hsb[hc & 1];
#pragma unroll
    for (int ks = 0; ks < 4; ++ks) {
      bf16x8 ha[4], wb[4];
#pragma unroll
      for (int i = 0; i < 4; ++i) {
        const int tok = i * 16 + lr;
        ha[i] = *(const bf16x8*)(hsb + ((tok * 256 + ks * 64 + lg * 16) ^ ((tok & 3) << 5)));
      }
#pragma unroll
      for (int j = 0; j < 4; ++j)
        wb[j] = *(const bf16x8*)(W2T + (size_t)(w * 64 + j * 16 + lr) * 2048 + hc * 128 + ks * 32 + lg * 8);
#pragma unroll
      for (int i = 0; i < 4; ++i)
#pragma unroll
        for (int j = 0; j < 4; ++j)
          acc2[i][j] = __builtin_amdgcn_mfma_f32_16x16x32_bf16(ha[i], wb[j], acc2[i][j], 0, 0, 0);
    }
  }
  // ---- epilogue: + fc2 bias + residual
#pragma unroll
  for (int j = 0; j < 4; ++j) {
    const int col = w * 64 + j * 16 + lr;
    const float bc = fb2[col];
#pragma unroll
    for (int i = 0; i < 4; ++i)
#pragma unroll
      for (int e = 0; e < 4; ++e) {
        const int row = m0 + i * 16 + lg * 4 + e;
        out[(size_t)row * 512 + col] = acc2[i][j][e] + bc + X2[(size_t)row * 512 + col];
      }
  }
}

// ---------------------------------------------------------------- 128x128 GEMM (m97 structure)
// EPI 0: proj  -> X2 fp32 at window-reversed+unshifted row, + x residual + bias
// EPI 3: qkv   -> outh: Q (scaled) | K | VT[win][head][d][n], all bf16
template<int EPI>
__global__ __launch_bounds__(256, 2)
void gemm128(const short* __restrict__ A, const short* __restrict__ BT,
             const int N, const int K,
             const float* __restrict__ bias,
             const float* __restrict__ resid,
             float* __restrict__ outf, short* __restrict__ outh) {
  __shared__ short As[128 * 32];
  __shared__ short Bs[128 * 32];
  const int tid = threadIdx.x, lane = tid & 63, wid = tid >> 6;
  const int lr = lane & 15, lg = lane >> 4;
  const int wm = wid >> 1, wn = wid & 1;
  const int m0 = blockIdx.y * 128, n0 = blockIdx.x * 128;
  const int srow = lane >> 2;            // 0..15
  const int scol = (lane & 3) * 8;       // 0,8,16,24
  f32x4 acc[4][4] = {};
  for (int kt = 0; kt < K; kt += 32) {
#pragma unroll
    for (int c = 0; c < 2; ++c) {
      const int chunk = wid * 2 + c;     // 0..7, 16 rows each
      GLDS16(A  + (size_t)(m0 + chunk * 16 + srow) * K + kt + scol, As + chunk * 512);
      GLDS16(BT + (size_t)(n0 + chunk * 16 + srow) * K + kt + scol, Bs + chunk * 512);
    }
    __syncthreads();
    bf16x8 af[4], bf_[4];
#pragma unroll
    for (int t = 0; t < 4; ++t) af[t]  = *(const bf16x8*)(As + (wm * 64 + t * 16 + lr) * 32 + lg * 8);
#pragma unroll
    for (int t = 0; t < 4; ++t) bf_[t] = *(const bf16x8*)(Bs + (wn * 64 + t * 16 + lr) * 32 + lg * 8);
#pragma unroll
    for (int i = 0; i < 4; ++i)
#pragma unroll
      for (int j = 0; j < 4; ++j)
        acc[i][j] = __builtin_amdgcn_mfma_f32_16x16x32_bf16(af[i], bf_[j], acc[i][j], 0, 0, 0);
    __syncthreads();
  }
#pragma unroll
  for (int j = 0; j < 4; ++j) {
    const int col = n0 + wn * 64 + j * 16 + lr;
    const float bc = bias[col];
#pragma unroll
    for (int i = 0; i < 4; ++i)
#pragma unroll
      for (int e = 0; e < 4; ++e) {
        const int row = m0 + wm * 64 + i * 16 + lg * 4 + e;
        float v = acc[i][j][e] + bc;
        if (EPI == 0) {
          const int w = row >> 6, n = row & 63;
          const int bb = w >> 6, wi = w & 63;
          const int hs = (wi >> 3) * 8 + (n >> 3), ws2 = (wi & 7) * 8 + (n & 7);
          const int hh = (hs + 4) & 63, wwp = (ws2 + 4) & 63;
          const size_t orow = (size_t)bb * 4096 + hh * 64 + wwp;
          outf[orow * 512 + col] = resid[orow * 512 + col] + v;
        } else {
          // QKV epilogue: seg uniform per block (n0 multiple of 128 within 512-col segs)
          const int seg = col >> 9;
          if (seg == 0) {
            outh[(size_t)row * 512 + col] = f2bf(v * 0.17677669529663687f);  // Q * 1/sqrt(32)
          } else if (seg == 1) {
            outh[33554432 + (size_t)row * 512 + (col - 512)] = f2bf(v);      // K
          } else {
            const int cc = col - 1024;                                        // V^T
            outh[67108864 + (size_t)((row >> 6) * 16 + (cc >> 5)) * 2048 + (cc & 31) * 64 + (row & 63)] = f2bf(v);
          }
        }
      }
  }
}

// ---------------------------------------------------------------- launch
extern "C" void kernel_launch(void* const* d_in, const int* in_sizes, int n_in,
                              void* d_out, int out_size, void* d_ws, size_t ws_size,
                              hipStream_t stream) {
  (void)in_sizes; (void)n_in; (void)out_size; (void)ws_size;
  const float* x      = (const float*)d_in[0];
  const float* g1     = (const float*)d_in[1];
  const float* b1     = (const float*)d_in[2];
  const float* qkv_w  = (const float*)d_in[3];
  const float* qkv_b  = (const float*)d_in[4];
  const float* proj_w = (const float*)d_in[5];
  const float* proj_b = (const float*)d_in[6];
  const float* rpb    = (const float*)d_in[7];
  const float* g2     = (const float*)d_in[8];
  const float* b2     = (const float*)d_in[9];
  const float* fc1_w  = (const float*)d_in[10];
  const float* fc1_b  = (const float*)d_in[11];
  const float* fc2_w  = (const float*)d_in[12];
  const float* fc2_b  = (const float*)d_in[13];
  float* out = (float*)d_out;
  char* ws = (char*)d_ws;

  short* WQKVT  = (short*)(ws);                 // [1536][512] bf16   1.5MB
  short* WPROJT = (short*)(ws + 1572864);       // [512][512]         0.5MB
  short* WFC1T  = (short*)(ws + 2097152);       // [2048][512]        2MB
  short* WFC2T  = (short*)(ws + 4194304);       // [512][2048]        2MB
  float* X2     = (float*)(ws + 6291456);       // [65536][512] fp32  134MB
  float* BIASF  = (float*)(ws + 6291456);       // 256KB, aliases X2 head (dead before proj writes X2)
  short* ATT    = (short*)(ws + 140509184);     // [65536][512] bf16  64MB
  short* XW     = (short*)(ws + 207618048);     // [65536][512] bf16  64MB
  short* QB     = (short*)(ws + 274726912);     // Q|K|VT 3x64MB

  transpose_bf16<<<3072, 256, 0, stream>>>(qkv_w,  WQKVT, 512, 1536);
  transpose_bf16<<<1024, 256, 0, stream>>>(proj_w, WPROJT, 512, 512);
  transpose_bf16<<<4096, 256, 0, stream>>>(fc1_w,  WFC1T, 512, 2048);
  transpose_bf16<<<4096, 256, 0, stream>>>(fc2_w,  WFC2T, 2048, 512);
  bias_expand<<<256, 256, 0, stream>>>(rpb, BIASF);

  ln_kernel<1><<<16384, 256, 0, stream>>>(x, g1, b1, XW);
  gemm128<3><<<dim3(12, 512), 256, 0, stream>>>(XW, WQKVT, 1536, 512, qkv_b, nullptr, nullptr, QB);
  attn_core<<<4096, 256, 0, stream>>>(QB, QB + 33554432, QB + 67108864, BIASF, ATT);
  gemm128<0><<<dim3(4, 512), 256, 0, stream>>>(ATT, WPROJT, 512, 512, proj_b, x, X2, nullptr);
  mlp_fused<<<1024, 512, 0, stream>>>(X2, g2, b2, WFC1T, fc1_b, WFC2T, fc2_b, out);
}

// Round 7
// 992.053 us; speedup vs baseline: 1.1373x; 1.1373x over previous
//
#include <hip/hip_runtime.h>
#include <hip/hip_bf16.h>

using f32x4  = __attribute__((ext_vector_type(4))) float;
using bf16x8 = __attribute__((ext_vector_type(8))) short;
using short8 = __attribute__((ext_vector_type(8))) short;
using s16x4  = __attribute__((ext_vector_type(4))) short;

#define DEVINL __device__ __forceinline__

DEVINL short f2bf(float f) {
  unsigned u = __builtin_bit_cast(unsigned, f);
  u += 0x7fffu + ((u >> 16) & 1u);          // RNE
  return (short)(u >> 16);
}

DEVINL float gelu_tanh(float v) {
  float c = v * (0.79788456080286536f + 0.0356774081363001f * v * v);
  return 0.5f * v * (1.0f + tanhf(c));
}

#define GLDS16(g, l) __builtin_amdgcn_global_load_lds( \
    (const __attribute__((address_space(1))) void*)(g), \
    (__attribute__((address_space(3))) void*)(l), 16, 0, 0)

#define SBAR() __builtin_amdgcn_s_barrier()
#define WAITV(n) asm volatile("s_waitcnt vmcnt(" #n ")" ::: "memory")
#define WAITL0() do { asm volatile("s_waitcnt lgkmcnt(0)" ::: "memory"); \
                      __builtin_amdgcn_sched_barrier(0); } while (0)

// ---------------------------------------------------------------- transpose
__global__ __launch_bounds__(256)
void transpose_bf16(const float* __restrict__ in, short* __restrict__ out, int R, int C) {
  int idx = blockIdx.x * 256 + threadIdx.x;
  if (idx >= R * C) return;
  int c = idx / R, r = idx % R;
  out[idx] = f2bf(in[(size_t)r * C + c]);
}

// ---------------------------------------------------------------- bias expand
__global__ __launch_bounds__(256)
void bias_expand(const float* __restrict__ rpb, float* __restrict__ BIASF) {
  int idx = blockIdx.x * 256 + threadIdx.x;   // 65536
  int head = idx >> 12, n = (idx >> 6) & 63, m = idx & 63;
  int i1 = n >> 3, j1 = n & 7, i2 = m >> 3, j2 = m & 7;
  BIASF[idx] = rpb[((i1 - i2 + 7) * 15 + (j1 - j2 + 7)) * 16 + head];
}

// ---------------------------------------------------------------- LayerNorm
template<int REMAP>
__global__ __launch_bounds__(256)
void ln_kernel(const float* __restrict__ X, const float* __restrict__ gamma,
               const float* __restrict__ beta, short* __restrict__ OUT) {
  const int lane = threadIdx.x & 63;
  const int wid  = threadIdx.x >> 6;
  const int t    = blockIdx.x * 4 + wid;
  const float* xp = X + (size_t)t * 512 + lane * 8;
  float4 a = *(const float4*)xp;
  float4 b = *(const float4*)(xp + 4);
  float s = a.x + a.y + a.z + a.w + b.x + b.y + b.z + b.w;
  float q = a.x*a.x + a.y*a.y + a.z*a.z + a.w*a.w
          + b.x*b.x + b.y*b.y + b.z*b.z + b.w*b.w;
#pragma unroll
  for (int d = 1; d < 64; d <<= 1) { s += __shfl_xor(s, d); q += __shfl_xor(q, d); }
  float mean = s * (1.0f / 512.0f);
  float var  = q * (1.0f / 512.0f) - mean * mean;
  float rstd = rsqrtf(var + 1e-5f);
  float4 g0 = *(const float4*)(gamma + lane * 8);
  float4 g1 = *(const float4*)(gamma + lane * 8 + 4);
  float4 b0 = *(const float4*)(beta + lane * 8);
  float4 b1 = *(const float4*)(beta + lane * 8 + 4);
  short8 o;
  o[0] = f2bf((a.x - mean) * rstd * g0.x + b0.x);
  o[1] = f2bf((a.y - mean) * rstd * g0.y + b0.y);
  o[2] = f2bf((a.z - mean) * rstd * g0.z + b0.z);
  o[3] = f2bf((a.w - mean) * rstd * g0.w + b0.w);
  o[4] = f2bf((b.x - mean) * rstd * g1.x + b1.x);
  o[5] = f2bf((b.y - mean) * rstd * g1.y + b1.y);
  o[6] = f2bf((b.z - mean) * rstd * g1.z + b1.z);
  o[7] = f2bf((b.w - mean) * rstd * g1.w + b1.w);
  size_t orow;
  if (REMAP) {
    int bb = t >> 12, l = t & 4095, hh = l >> 6, ww = l & 63;
    int hs = (hh + 60) & 63, ws2 = (ww + 60) & 63;   // (coord - 4) mod 64
    orow = (size_t)(bb * 64 + (hs >> 3) * 8 + (ws2 >> 3)) * 64 + (hs & 7) * 8 + (ws2 & 7);
  } else {
    orow = (size_t)t;
  }
  *(short8*)(OUT + orow * 512 + lane * 8) = o;
}

// ---------------------------------------------------------------- attention core
__global__ __launch_bounds__(256)
void attn_core(const short* __restrict__ Q, const short* __restrict__ Kb,
               const short* __restrict__ VT, const float* __restrict__ BIASF,
               short* __restrict__ AOUT) {
  __shared__ short P[4][4096];
  const int tid = threadIdx.x, lane = tid & 63, wid = tid >> 6;
  const int lr = lane & 15, lg = lane >> 4;
  const int gw = blockIdx.x * 4 + wid;
  const int win = gw >> 4, head = gw & 15;
  const int wimg = win & 63, wh = wimg >> 3, ww = wimg & 7;
  const size_t qbase = (size_t)win * 64 * 512 + head * 32;
  short* Pb = P[wid];

  bf16x8 aq[4], bk[4];
#pragma unroll
  for (int tm = 0; tm < 4; ++tm) aq[tm] = *(const bf16x8*)(Q  + qbase + (size_t)(tm * 16 + lr) * 512 + lg * 8);
#pragma unroll
  for (int tn = 0; tn < 4; ++tn) bk[tn] = *(const bf16x8*)(Kb + qbase + (size_t)(tn * 16 + lr) * 512 + lg * 8);
  f32x4 sa[4][4] = {};
#pragma unroll
  for (int tm = 0; tm < 4; ++tm)
#pragma unroll
    for (int tn = 0; tn < 4; ++tn)
      sa[tm][tn] = __builtin_amdgcn_mfma_f32_16x16x32_bf16(aq[tm], bk[tn], sa[tm][tn], 0, 0, 0);

  const float* bias_h = BIASF + head * 4096;
  float inv[4][4];
#pragma unroll
  for (int tm = 0; tm < 4; ++tm) {
#pragma unroll
    for (int e = 0; e < 4; ++e) {
      const int n = tm * 16 + lg * 4 + e;
      const int i1 = n >> 3, j1 = n & 7;
      const int rh1 = (wh == 7) ? 1 + (i1 >> 2) : 0;
      const int rw1 = (ww == 7) ? 1 + (j1 >> 2) : 0;
      float v[4];
      float mx = -3.0e38f;
#pragma unroll
      for (int tn = 0; tn < 4; ++tn) {
        const int m = tn * 16 + lr;
        const int mi = (m >> 3), mj = m & 7;
        const int rh2 = (wh == 7) ? 1 + (mi >> 2) : 0;
        const int rw2 = (ww == 7) ? 1 + (mj >> 2) : 0;
        float val = sa[tm][tn][e] + bias_h[n * 64 + m]
                  + ((rh1 != rh2 || rw1 != rw2) ? -100.0f : 0.0f);
        v[tn] = val;
        mx = fmaxf(mx, val);
      }
#pragma unroll
      for (int d = 1; d < 16; d <<= 1) mx = fmaxf(mx, __shfl_xor(mx, d));
      float sum = 0.f;
#pragma unroll
      for (int tn = 0; tn < 4; ++tn) { v[tn] = __expf(v[tn] - mx); sum += v[tn]; }
#pragma unroll
      for (int d = 1; d < 16; d <<= 1) sum += __shfl_xor(sum, d);
      inv[tm][e] = 1.0f / sum;
      const int sw = (n & 7) << 3;
#pragma unroll
      for (int tn = 0; tn < 4; ++tn) Pb[n * 64 + ((tn * 16 + lr) ^ sw)] = f2bf(v[tn]);
    }
  }
  __syncthreads();

  f32x4 oa[4][2] = {};
  const short* vt = VT + (size_t)win * 32768 + head * 2048;
#pragma unroll
  for (int ks = 0; ks < 2; ++ks) {
    bf16x8 pa[4], bv[2];
#pragma unroll
    for (int tm = 0; tm < 4; ++tm) {
      const int r = tm * 16 + lr;
      pa[tm] = *(const bf16x8*)(Pb + r * 64 + ((ks * 32 + lg * 8) ^ ((r & 7) << 3)));
    }
#pragma unroll
    for (int t2 = 0; t2 < 2; ++t2) bv[t2] = *(const bf16x8*)(vt + (t2 * 16 + lr) * 64 + ks * 32 + lg * 8);
#pragma unroll
    for (int tm = 0; tm < 4; ++tm)
#pragma unroll
      for (int t2 = 0; t2 < 2; ++t2)
        oa[tm][t2] = __builtin_amdgcn_mfma_f32_16x16x32_bf16(pa[tm], bv[t2], oa[tm][t2], 0, 0, 0);
  }
#pragma unroll
  for (int tm = 0; tm < 4; ++tm)
#pragma unroll
    for (int t2 = 0; t2 < 2; ++t2)
#pragma unroll
      for (int e = 0; e < 4; ++e) {
        const int n = tm * 16 + lg * 4 + e;
        AOUT[((size_t)win * 64 + n) * 512 + head * 32 + t2 * 16 + lr] = f2bf(oa[tm][t2][e] * inv[tm][e]);
      }
}

// ---------------------------------------------------------------- 256x256 phase-interleaved GEMM
// A [M][K], BT [N][K] bf16 row-major. BK=32; 3-slot LDS ring (96 KB) => 2-tile
// lookahead, counted vmcnt(4); raw s_barrier (loads stay in flight across it);
// setprio around MFMA clusters. 8 waves (2m x 4n), wave tile 128x64.
// Swizzle: LDS [128][32] per half, linear dest; source col ^= ((row>>1)&3)*8 elems;
// read col-byte ^= ((row>>1)&3)*16 (same involution both sides).
// EPI 1 (fc1, operand-swapped): C[h][tok] -> outh H1[tok][2048] bf16, gelu(acc+bias), packed s16x4
// EPI 2 (fc2): C[tok][out]  -> outf[tok*512+out] = acc + bias + resid
template<int EPI, int K>
__global__ __launch_bounds__(512, 1)
void gemm256(const short* __restrict__ Aa, const short* __restrict__ Bb,
             const float* __restrict__ bias, const float* __restrict__ resid,
             float* __restrict__ outf, short* __restrict__ outh) {
  constexpr int NT = K / 32;
  __shared__ short L[3][2][2][128 * 32];   // [slot][mat A=0/B=1][half][128 rows][32]
  const int tid = threadIdx.x;
  const int lane = tid & 63, w = tid >> 6;
  const int lr = lane & 15, lg = lane >> 4;
  const int wm = w >> 2, wn = w & 3;

  // XCD-aware bijective block swizzle (nwg % 8 == 0 in both uses)
  const int nwg = gridDim.x;
  const int id = blockIdx.x;
  const int id2 = (id & 7) * (nwg >> 3) + (id >> 3);
  int mt, ntile;
  if (EPI == 1) { mt = id2 & 7; ntile = id2 >> 3; }   // 8 consecutive share B-panel
  else          { ntile = id2 & 1; mt = id2 >> 1; }   // 2 consecutive share A-panel
  const int m0 = mt * 256, n0 = ntile * 256;

  // staging: one GLDS16 per thread per half-tile (8 KB). Wave w -> rows w*16+(lane>>2).
  const int srow = w * 16 + (lane >> 2);
  const int pcb  = (lane & 3) * 16;                               // phys col byte (linear dest)
  const int scol = ((lane & 3) * 8) ^ (((srow >> 1) & 3) * 8);    // pre-swizzled source col (elems)

  auto stage = [&](int slot, int mat, int half, int kt) {
    const short* src = mat ? Bb : Aa;
    const int rbase = (mat ? n0 : m0) + half * 128;
    GLDS16(src + (size_t)(rbase + srow) * K + kt * 32 + scol,
           (short*)&L[slot][mat][half][0] + srow * 32 + (pcb >> 1));
  };
  auto lda = [&](int slot, int mr) -> bf16x8 {
    const int row = mr * 16 + lr;
    const int cb = (lg * 16) ^ (((row >> 1) & 3) * 16);
    return *(const bf16x8*)((const char*)&L[slot][0][wm][0] + row * 64 + cb);
  };
  auto ldb = [&](int slot, int nr) -> bf16x8 {
    const int row = (wn & 1) * 64 + nr * 16 + lr;
    const int cb = (lg * 16) ^ (((row >> 1) & 3) * 16);
    return *(const bf16x8*)((const char*)&L[slot][1][wn >> 1][0] + row * 64 + cb);
  };

  f32x4 acc[8][4] = {};
  // prologue: stage tiles 0 and 1 (4 half-tiles each = 4 loads/thread each)
#pragma unroll
  for (int u = 0; u < 2; ++u) {
    stage(u, 0, 0, u); stage(u, 0, 1, u);
    stage(u, 1, 0, u); stage(u, 1, 1, u);
  }
  WAITV(4);            // tile 0 landed; tile 1 in flight
  SBAR();

  bf16x8 b[4];
  for (int t = 0; t < NT; ++t) {
    const int slot = t % 3;
    const int s2 = (t + 2) % 3;      // == (t-1)%3: consumed last span, safe to overwrite
    // ---- phase 0: a-frags 0..3 + b-frags, stage A-halves of t+2
    bf16x8 a0[4];
#pragma unroll
    for (int i = 0; i < 4; ++i) a0[i] = lda(slot, i);
#pragma unroll
    for (int j = 0; j < 4; ++j) b[j] = ldb(slot, j);
    if (t + 2 < NT) { stage(s2, 0, 0, t + 2); stage(s2, 0, 1, t + 2); }
    SBAR();
    WAITL0();
    __builtin_amdgcn_s_setprio(1);
#pragma unroll
    for (int i = 0; i < 4; ++i)
#pragma unroll
      for (int j = 0; j < 4; ++j)
        acc[i][j] = __builtin_amdgcn_mfma_f32_16x16x32_bf16(a0[i], b[j], acc[i][j], 0, 0, 0);
    __builtin_amdgcn_s_setprio(0);
    SBAR();
    // ---- phase 1: a-frags 4..7 (reuse b), stage B-halves of t+2
    bf16x8 a1[4];
#pragma unroll
    for (int i = 0; i < 4; ++i) a1[i] = lda(slot, 4 + i);
    if (t + 2 < NT) { stage(s2, 1, 0, t + 2); stage(s2, 1, 1, t + 2); }
    SBAR();
    WAITL0();
    __builtin_amdgcn_s_setprio(1);
#pragma unroll
    for (int i = 0; i < 4; ++i)
#pragma unroll
      for (int j = 0; j < 4; ++j)
        acc[4 + i][j] = __builtin_amdgcn_mfma_f32_16x16x32_bf16(a1[i], b[j], acc[4 + i][j], 0, 0, 0);
    __builtin_amdgcn_s_setprio(0);
    // span-end: ensure tile t+1 fully landed before next span reads it
    if (t < NT - 2)       { WAITV(4); }
    else if (t == NT - 2) { WAITV(0); }
    SBAR();
  }

  // ---- epilogue
  if (EPI == 1) {
    // C row = h (m-dim), col = tok (n-dim); pack 4 consecutive h per thread
#pragma unroll
    for (int mr = 0; mr < 8; ++mr) {
      const int h0 = m0 + wm * 128 + mr * 16 + lg * 4;
      const float4 bi = *(const float4*)(bias + h0);
#pragma unroll
      for (int nr = 0; nr < 4; ++nr) {
        const int tok = n0 + wn * 64 + nr * 16 + lr;
        s16x4 o;
        o[0] = f2bf(gelu_tanh(acc[mr][nr][0] + bi.x));
        o[1] = f2bf(gelu_tanh(acc[mr][nr][1] + bi.y));
        o[2] = f2bf(gelu_tanh(acc[mr][nr][2] + bi.z));
        o[3] = f2bf(gelu_tanh(acc[mr][nr][3] + bi.w));
        *(s16x4*)(outh + (size_t)tok * 2048 + h0) = o;
      }
    }
  } else {
#pragma unroll
    for (int nr = 0; nr < 4; ++nr) {
      const int col = n0 + wn * 64 + nr * 16 + lr;
      const float bc = bias[col];
#pragma unroll
      for (int mr = 0; mr < 8; ++mr)
#pragma unroll
        for (int e = 0; e < 4; ++e) {
          const int row = m0 + wm * 128 + mr * 16 + lg * 4 + e;
          outf[(size_t)row * 512 + col] = acc[mr][nr][e] + bc + resid[(size_t)row * 512 + col];
        }
    }
  }
}

// ---------------------------------------------------------------- 128x128 GEMM (m97 structure)
// EPI 0: proj -> X2 fp32 window-reversed+unshifted + x residual + bias
// EPI 3: qkv  -> Q (scaled) | K | VT[win][head][d][n], bf16
template<int EPI>
__global__ __launch_bounds__(256, 2)
void gemm128(const short* __restrict__ A, const short* __restrict__ BT,
             const int N, const int K,
             const float* __restrict__ bias,
             const float* __restrict__ resid,
             float* __restrict__ outf, short* __restrict__ outh) {
  __shared__ short As[128 * 32];
  __shared__ short Bs[128 * 32];
  const int tid = threadIdx.x, lane = tid & 63, wid = tid >> 6;
  const int lr = lane & 15, lg = lane >> 4;
  const int wm = wid >> 1, wn = wid & 1;
  const int m0 = blockIdx.y * 128, n0 = blockIdx.x * 128;
  const int srow = lane >> 2;
  const int scol = (lane & 3) * 8;
  f32x4 acc[4][4] = {};
  for (int kt = 0; kt < K; kt += 32) {
#pragma unroll
    for (int c = 0; c < 2; ++c) {
      const int chunk = wid * 2 + c;
      GLDS16(A  + (size_t)(m0 + chunk * 16 + srow) * K + kt + scol, As + chunk * 512);
      GLDS16(BT + (size_t)(n0 + chunk * 16 + srow) * K + kt + scol, Bs + chunk * 512);
    }
    __syncthreads();
    bf16x8 af[4], bf_[4];
#pragma unroll
    for (int t = 0; t < 4; ++t) af[t]  = *(const bf16x8*)(As + (wm * 64 + t * 16 + lr) * 32 + lg * 8);
#pragma unroll
    for (int t = 0; t < 4; ++t) bf_[t] = *(const bf16x8*)(Bs + (wn * 64 + t * 16 + lr) * 32 + lg * 8);
#pragma unroll
    for (int i = 0; i < 4; ++i)
#pragma unroll
      for (int j = 0; j < 4; ++j)
        acc[i][j] = __builtin_amdgcn_mfma_f32_16x16x32_bf16(af[i], bf_[j], acc[i][j], 0, 0, 0);
    __syncthreads();
  }
#pragma unroll
  for (int j = 0; j < 4; ++j) {
    const int col = n0 + wn * 64 + j * 16 + lr;
    const float bc = bias[col];
#pragma unroll
    for (int i = 0; i < 4; ++i)
#pragma unroll
      for (int e = 0; e < 4; ++e) {
        const int row = m0 + wm * 64 + i * 16 + lg * 4 + e;
        float v = acc[i][j][e] + bc;
        if (EPI == 0) {
          const int w = row >> 6, n = row & 63;
          const int bb = w >> 6, wi = w & 63;
          const int hs = (wi >> 3) * 8 + (n >> 3), ws2 = (wi & 7) * 8 + (n & 7);
          const int hh = (hs + 4) & 63, wwp = (ws2 + 4) & 63;
          const size_t orow = (size_t)bb * 4096 + hh * 64 + wwp;
          outf[orow * 512 + col] = resid[orow * 512 + col] + v;
        } else {
          const int seg = col >> 9;
          if (seg == 0) {
            outh[(size_t)row * 512 + col] = f2bf(v * 0.17677669529663687f);  // Q * 1/sqrt(32)
          } else if (seg == 1) {
            outh[33554432 + (size_t)row * 512 + (col - 512)] = f2bf(v);      // K
          } else {
            const int cc = col - 1024;                                        // V^T
            outh[67108864 + (size_t)((row >> 6) * 16 + (cc >> 5)) * 2048 + (cc & 31) * 64 + (row & 63)] = f2bf(v);
          }
        }
      }
  }
}

// ---------------------------------------------------------------- launch
extern "C" void kernel_launch(void* const* d_in, const int* in_sizes, int n_in,
                              void* d_out, int out_size, void* d_ws, size_t ws_size,
                              hipStream_t stream) {
  (void)in_sizes; (void)n_in; (void)out_size; (void)ws_size;
  const float* x      = (const float*)d_in[0];
  const float* g1     = (const float*)d_in[1];
  const float* b1     = (const float*)d_in[2];
  const float* qkv_w  = (const float*)d_in[3];
  const float* qkv_b  = (const float*)d_in[4];
  const float* proj_w = (const float*)d_in[5];
  const float* proj_b = (const float*)d_in[6];
  const float* rpb    = (const float*)d_in[7];
  const float* g2     = (const float*)d_in[8];
  const float* b2     = (const float*)d_in[9];
  const float* fc1_w  = (const float*)d_in[10];
  const float* fc1_b  = (const float*)d_in[11];
  const float* fc2_w  = (const float*)d_in[12];
  const float* fc2_b  = (const float*)d_in[13];
  float* out = (float*)d_out;
  char* ws = (char*)d_ws;

  short* WQKVT  = (short*)(ws);                 // [1536][512] bf16   1.5MB
  short* WPROJT = (short*)(ws + 1572864);       // [512][512]         0.5MB
  short* WFC1T  = (short*)(ws + 2097152);       // [2048][512]        2MB
  short* WFC2T  = (short*)(ws + 4194304);       // [512][2048]        2MB
  float* X2     = (float*)(ws + 6291456);       // [65536][512] fp32  134MB
  float* BIASF  = (float*)(ws + 6291456);       // 256KB alias (dead before proj)
  short* ATT    = (short*)(ws + 140509184);     // [65536][512] bf16  64MB (X2N reuse)
  short* XW     = (short*)(ws + 207618048);     // [65536][512] bf16  64MB
  short* QB     = (short*)(ws + 274726912);     // Q|K|VT 3x64MB
  short* H1     = XW;                           // [65536][2048] bf16 256MB over XW+QB (dead)
  short* X2N    = ATT;

  transpose_bf16<<<3072, 256, 0, stream>>>(qkv_w,  WQKVT, 512, 1536);
  transpose_bf16<<<1024, 256, 0, stream>>>(proj_w, WPROJT, 512, 512);
  transpose_bf16<<<4096, 256, 0, stream>>>(fc1_w,  WFC1T, 512, 2048);
  transpose_bf16<<<4096, 256, 0, stream>>>(fc2_w,  WFC2T, 2048, 512);
  bias_expand<<<256, 256, 0, stream>>>(rpb, BIASF);

  ln_kernel<1><<<16384, 256, 0, stream>>>(x, g1, b1, XW);
  gemm128<3><<<dim3(12, 512), 256, 0, stream>>>(XW, WQKVT, 1536, 512, qkv_b, nullptr, nullptr, QB);
  attn_core<<<4096, 256, 0, stream>>>(QB, QB + 33554432, QB + 67108864, BIASF, ATT);
  gemm128<0><<<dim3(4, 512), 256, 0, stream>>>(ATT, WPROJT, 512, 512, proj_b, x, X2, nullptr);
  ln_kernel<0><<<16384, 256, 0, stream>>>(X2, g2, b2, X2N);
  // fc1 operand-swapped: A=W1T [2048][512], B=X2N [65536][512] -> H1[tok][h] bf16
  gemm256<1, 512><<<2048, 512, 0, stream>>>(WFC1T, X2N, fc1_b, nullptr, nullptr, H1);
  // fc2: A=H1 [65536][2048], BT=W2T [512][2048] -> out fp32 + bias + X2 residual
  gemm256<2, 2048><<<512, 512, 0, stream>>>(H1, WFC2T, fc2_b, X2, out, nullptr);
}

// Round 8
// 873.758 us; speedup vs baseline: 1.2913x; 1.1354x over previous
//
#include <hip/hip_runtime.h>
#include <hip/hip_bf16.h>

using f32x4  = __attribute__((ext_vector_type(4))) float;
using bf16x8 = __attribute__((ext_vector_type(8))) short;
using short8 = __attribute__((ext_vector_type(8))) short;
using s16x4  = __attribute__((ext_vector_type(4))) short;

#define DEVINL __device__ __forceinline__

DEVINL short f2bf(float f) {
  unsigned u = __builtin_bit_cast(unsigned, f);
  u += 0x7fffu + ((u >> 16) & 1u);          // RNE
  return (short)(u >> 16);
}

// tanh-approx GELU in sigmoid form: 0.5v(1+tanh(u)) == v/(1+exp(-2u))
DEVINL float gelu_fast(float v) {
  float t = __expf(-1.5957691216057308f * (v + 0.044715f * v * v * v));
  return v * __builtin_amdgcn_rcpf(1.0f + t);
}

#define GLDS16(g, l) __builtin_amdgcn_global_load_lds( \
    (const __attribute__((address_space(1))) void*)(g), \
    (__attribute__((address_space(3))) void*)(l), 16, 0, 0)

#define SBAR() __builtin_amdgcn_s_barrier()
#define WAITV(n) asm volatile("s_waitcnt vmcnt(" #n ")" ::: "memory")

// ---------------------------------------------------------------- transpose
__global__ __launch_bounds__(256)
void transpose_bf16(const float* __restrict__ in, short* __restrict__ out, int R, int C) {
  int idx = blockIdx.x * 256 + threadIdx.x;
  if (idx >= R * C) return;
  int c = idx / R, r = idx % R;
  out[idx] = f2bf(in[(size_t)r * C + c]);
}

// ---------------------------------------------------------------- bias expand
__global__ __launch_bounds__(256)
void bias_expand(const float* __restrict__ rpb, float* __restrict__ BIASF) {
  int idx = blockIdx.x * 256 + threadIdx.x;   // 65536
  int head = idx >> 12, n = (idx >> 6) & 63, m = idx & 63;
  int i1 = n >> 3, j1 = n & 7, i2 = m >> 3, j2 = m & 7;
  BIASF[idx] = rpb[((i1 - i2 + 7) * 15 + (j1 - j2 + 7)) * 16 + head];
}

// ---------------------------------------------------------------- LayerNorm
template<int REMAP>
__global__ __launch_bounds__(256)
void ln_kernel(const float* __restrict__ X, const float* __restrict__ gamma,
               const float* __restrict__ beta, short* __restrict__ OUT) {
  const int lane = threadIdx.x & 63;
  const int wid  = threadIdx.x >> 6;
  const int t    = blockIdx.x * 4 + wid;
  const float* xp = X + (size_t)t * 512 + lane * 8;
  float4 a = *(const float4*)xp;
  float4 b = *(const float4*)(xp + 4);
  float s = a.x + a.y + a.z + a.w + b.x + b.y + b.z + b.w;
  float q = a.x*a.x + a.y*a.y + a.z*a.z + a.w*a.w
          + b.x*b.x + b.y*b.y + b.z*b.z + b.w*b.w;
#pragma unroll
  for (int d = 1; d < 64; d <<= 1) { s += __shfl_xor(s, d); q += __shfl_xor(q, d); }
  float mean = s * (1.0f / 512.0f);
  float var  = q * (1.0f / 512.0f) - mean * mean;
  float rstd = rsqrtf(var + 1e-5f);
  float4 g0 = *(const float4*)(gamma + lane * 8);
  float4 g1 = *(const float4*)(gamma + lane * 8 + 4);
  float4 b0 = *(const float4*)(beta + lane * 8);
  float4 b1 = *(const float4*)(beta + lane * 8 + 4);
  short8 o;
  o[0] = f2bf((a.x - mean) * rstd * g0.x + b0.x);
  o[1] = f2bf((a.y - mean) * rstd * g0.y + b0.y);
  o[2] = f2bf((a.z - mean) * rstd * g0.z + b0.z);
  o[3] = f2bf((a.w - mean) * rstd * g0.w + b0.w);
  o[4] = f2bf((b.x - mean) * rstd * g1.x + b1.x);
  o[5] = f2bf((b.y - mean) * rstd * g1.y + b1.y);
  o[6] = f2bf((b.z - mean) * rstd * g1.z + b1.z);
  o[7] = f2bf((b.w - mean) * rstd * g1.w + b1.w);
  size_t orow;
  if (REMAP) {
    int bb = t >> 12, l = t & 4095, hh = l >> 6, ww = l & 63;
    int hs = (hh + 60) & 63, ws2 = (ww + 60) & 63;   // (coord - 4) mod 64
    orow = (size_t)(bb * 64 + (hs >> 3) * 8 + (ws2 >> 3)) * 64 + (hs & 7) * 8 + (ws2 & 7);
  } else {
    orow = (size_t)t;
  }
  *(short8*)(OUT + orow * 512 + lane * 8) = o;
}

// ---------------------------------------------------------------- attention core
__global__ __launch_bounds__(256)
void attn_core(const short* __restrict__ Q, const short* __restrict__ Kb,
               const short* __restrict__ VT, const float* __restrict__ BIASF,
               short* __restrict__ AOUT) {
  __shared__ short P[4][4096];
  const int tid = threadIdx.x, lane = tid & 63, wid = tid >> 6;
  const int lr = lane & 15, lg = lane >> 4;
  const int gw = blockIdx.x * 4 + wid;
  const int win = gw >> 4, head = gw & 15;
  const int wimg = win & 63, wh = wimg >> 3, ww = wimg & 7;
  const size_t qbase = (size_t)win * 64 * 512 + head * 32;
  short* Pb = P[wid];

  bf16x8 aq[4], bk[4];
#pragma unroll
  for (int tm = 0; tm < 4; ++tm) aq[tm] = *(const bf16x8*)(Q  + qbase + (size_t)(tm * 16 + lr) * 512 + lg * 8);
#pragma unroll
  for (int tn = 0; tn < 4; ++tn) bk[tn] = *(const bf16x8*)(Kb + qbase + (size_t)(tn * 16 + lr) * 512 + lg * 8);
  f32x4 sa[4][4] = {};
#pragma unroll
  for (int tm = 0; tm < 4; ++tm)
#pragma unroll
    for (int tn = 0; tn < 4; ++tn)
      sa[tm][tn] = __builtin_amdgcn_mfma_f32_16x16x32_bf16(aq[tm], bk[tn], sa[tm][tn], 0, 0, 0);

  const float* bias_h = BIASF + head * 4096;
  float inv[4][4];
#pragma unroll
  for (int tm = 0; tm < 4; ++tm) {
#pragma unroll
    for (int e = 0; e < 4; ++e) {
      const int n = tm * 16 + lg * 4 + e;
      const int i1 = n >> 3, j1 = n & 7;
      const int rh1 = (wh == 7) ? 1 + (i1 >> 2) : 0;
      const int rw1 = (ww == 7) ? 1 + (j1 >> 2) : 0;
      float v[4];
      float mx = -3.0e38f;
#pragma unroll
      for (int tn = 0; tn < 4; ++tn) {
        const int m = tn * 16 + lr;
        const int mi = (m >> 3), mj = m & 7;
        const int rh2 = (wh == 7) ? 1 + (mi >> 2) : 0;
        const int rw2 = (ww == 7) ? 1 + (mj >> 2) : 0;
        float val = sa[tm][tn][e] + bias_h[n * 64 + m]
                  + ((rh1 != rh2 || rw1 != rw2) ? -100.0f : 0.0f);
        v[tn] = val;
        mx = fmaxf(mx, val);
      }
#pragma unroll
      for (int d = 1; d < 16; d <<= 1) mx = fmaxf(mx, __shfl_xor(mx, d));
      float sum = 0.f;
#pragma unroll
      for (int tn = 0; tn < 4; ++tn) { v[tn] = __expf(v[tn] - mx); sum += v[tn]; }
#pragma unroll
      for (int d = 1; d < 16; d <<= 1) sum += __shfl_xor(sum, d);
      inv[tm][e] = 1.0f / sum;
      const int sw = (n & 7) << 3;
#pragma unroll
      for (int tn = 0; tn < 4; ++tn) Pb[n * 64 + ((tn * 16 + lr) ^ sw)] = f2bf(v[tn]);
    }
  }
  __syncthreads();

  f32x4 oa[4][2] = {};
  const short* vt = VT + (size_t)win * 32768 + head * 2048;
#pragma unroll
  for (int ks = 0; ks < 2; ++ks) {
    bf16x8 pa[4], bv[2];
#pragma unroll
    for (int tm = 0; tm < 4; ++tm) {
      const int r = tm * 16 + lr;
      pa[tm] = *(const bf16x8*)(Pb + r * 64 + ((ks * 32 + lg * 8) ^ ((r & 7) << 3)));
    }
#pragma unroll
    for (int t2 = 0; t2 < 2; ++t2) bv[t2] = *(const bf16x8*)(vt + (t2 * 16 + lr) * 64 + ks * 32 + lg * 8);
#pragma unroll
    for (int tm = 0; tm < 4; ++tm)
#pragma unroll
      for (int t2 = 0; t2 < 2; ++t2)
        oa[tm][t2] = __builtin_amdgcn_mfma_f32_16x16x32_bf16(pa[tm], bv[t2], oa[tm][t2], 0, 0, 0);
  }
#pragma unroll
  for (int tm = 0; tm < 4; ++tm)
#pragma unroll
    for (int t2 = 0; t2 < 2; ++t2)
#pragma unroll
      for (int e = 0; e < 4; ++e) {
        const int n = tm * 16 + lg * 4 + e;
        AOUT[((size_t)win * 64 + n) * 512 + head * 32 + t2 * 16 + lr] = f2bf(oa[tm][t2][e] * inv[tm][e]);
      }
}

// ---------------------------------------------------------------- 256x256 GEMM v2
// A [M][K], BT [N][K] bf16 row-major. BK=32; 3-slot LDS ring (96 KB), 2-tile
// lookahead, counted vmcnt(4); ONE phase + ONE raw s_barrier per K-tile;
// all LDS/global addressing hoisted; compiler manages lgkmcnt (no pins).
// 8 waves (2m x 4n), wave tile 128x64.
// Swizzle: linear LDS dest; source col ^= ((row>>1)&3)*8 elems; read applies same.
// EPI 0 (proj): C[tok][out] -> X2 window-reversed + x residual + bias
// EPI 1 (fc1, operand-swapped): C[h][tok] -> H1[tok][2048] bf16 gelu, packed s16x4
// EPI 2 (fc2): C[tok][out] -> outf = acc + bias + resid
template<int EPI, int K>
__global__ __launch_bounds__(512, 1)
void gemm256(const short* __restrict__ Aa, const short* __restrict__ Bb,
             const float* __restrict__ bias, const float* __restrict__ resid,
             float* __restrict__ outf, short* __restrict__ outh) {
  constexpr int NT = K / 32;
  __shared__ short L[3][2][2][128 * 32];   // slot 32KB { A:h0,h1 | B:h0,h1 } 8KB regions
  const int tid = threadIdx.x;
  const int lane = tid & 63, w = tid >> 6;
  const int lr = lane & 15, lg = lane >> 4;
  const int wm = w >> 2, wn = w & 3;

  // XCD-aware bijective swizzle (nwg % 8 == 0 in all uses)
  const int nwg = gridDim.x;
  const int id = blockIdx.x;
  const int id2 = (id & 7) * (nwg >> 3) + (id >> 3);
  int mt, ntile;
  if (EPI == 1) { mt = id2 & 7; ntile = id2 >> 3; }   // 8 consecutive share B-panel
  else          { ntile = id2 & 1; mt = id2 >> 1; }   // 2 consecutive share A-panel
  const int m0 = mt * 256, n0 = ntile * 256;

  // ---- hoisted staging addresses (one GLDS16 per thread per 8KB region)
  const int srow = w * 16 + (lane >> 2);                          // 0..127
  const int pcb  = (lane & 3) * 16;                               // linear dest col byte
  const int scol = ((lane & 3) * 8) ^ (((srow >> 1) & 3) * 8);    // pre-swizzled src col
  const short* gA0 = Aa + (size_t)(m0 +       srow) * K + scol;
  const short* gA1 = Aa + (size_t)(m0 + 128 + srow) * K + scol;
  const short* gB0 = Bb + (size_t)(n0 +       srow) * K + scol;
  const short* gB1 = Bb + (size_t)(n0 + 128 + srow) * K + scol;
  const int dOff = srow * 64 + pcb;                               // bytes within region
  char* Lb = (char*)&L[0][0][0][0];

  auto stageAll = [&](int slot, int kt) {
    char* s = Lb + slot * 32768 + dOff;
    GLDS16(gA0 + kt * 32, s);
    GLDS16(gA1 + kt * 32, s + 8192);
    GLDS16(gB0 + kt * 32, s + 16384);
    GLDS16(gB1 + kt * 32, s + 24576);
  };

  // ---- hoisted fragment-read offsets (bytes within slot)
  int aoff[8], boff[4];
#pragma unroll
  for (int mr = 0; mr < 8; ++mr) {
    const int row = mr * 16 + lr;
    aoff[mr] = wm * 8192 + row * 64 + ((lg * 16) ^ (((row >> 1) & 3) * 16));
  }
#pragma unroll
  for (int nr = 0; nr < 4; ++nr) {
    const int row = (wn & 1) * 64 + nr * 16 + lr;
    boff[nr] = 16384 + (wn >> 1) * 8192 + row * 64 + ((lg * 16) ^ (((row >> 1) & 3) * 16));
  }

  f32x4 acc[8][4] = {};
  stageAll(0, 0);
  stageAll(1, 1);
  WAITV(4);            // tile 0 landed; tile 1 in flight
  SBAR();

  for (int t = 0; t < NT; ++t) {
    const char* Ls = Lb + (t % 3) * 32768;
    bf16x8 a[8], b[4];
#pragma unroll
    for (int i = 0; i < 8; ++i) a[i] = *(const bf16x8*)(Ls + aoff[i]);
#pragma unroll
    for (int j = 0; j < 4; ++j) b[j] = *(const bf16x8*)(Ls + boff[j]);
    if (t + 2 < NT) stageAll((t + 2) % 3, t + 2);
    __builtin_amdgcn_s_setprio(1);
#pragma unroll
    for (int i = 0; i < 8; ++i)
#pragma unroll
      for (int j = 0; j < 4; ++j)
        acc[i][j] = __builtin_amdgcn_mfma_f32_16x16x32_bf16(a[i], b[j], acc[i][j], 0, 0, 0);
    __builtin_amdgcn_s_setprio(0);
    if (t < NT - 2)       { WAITV(4); }   // tile t+1 fully landed
    else if (t == NT - 2) { WAITV(0); }
    SBAR();
  }

  // ---- epilogue
  if (EPI == 1) {
    // C row = h, col = tok; pack 4 consecutive h per thread
#pragma unroll
    for (int mr = 0; mr < 8; ++mr) {
      const int h0 = m0 + wm * 128 + mr * 16 + lg * 4;
      const float4 bi = *(const float4*)(bias + h0);
#pragma unroll
      for (int nr = 0; nr < 4; ++nr) {
        const int tok = n0 + wn * 64 + nr * 16 + lr;
        s16x4 o;
        o[0] = f2bf(gelu_fast(acc[mr][nr][0] + bi.x));
        o[1] = f2bf(gelu_fast(acc[mr][nr][1] + bi.y));
        o[2] = f2bf(gelu_fast(acc[mr][nr][2] + bi.z));
        o[3] = f2bf(gelu_fast(acc[mr][nr][3] + bi.w));
        *(s16x4*)(outh + (size_t)tok * 2048 + h0) = o;
      }
    }
  } else if (EPI == 0) {
#pragma unroll
    for (int nr = 0; nr < 4; ++nr) {
      const int col = n0 + wn * 64 + nr * 16 + lr;
      const float bc = bias[col];
#pragma unroll
      for (int mr = 0; mr < 8; ++mr)
#pragma unroll
        for (int e = 0; e < 4; ++e) {
          const int row = m0 + wm * 128 + mr * 16 + lg * 4 + e;
          float v = acc[mr][nr][e] + bc;
          const int wv = row >> 6, n = row & 63;
          const int bb = wv >> 6, wi = wv & 63;
          const int hs = (wi >> 3) * 8 + (n >> 3), ws2 = (wi & 7) * 8 + (n & 7);
          const int hh = (hs + 4) & 63, wwp = (ws2 + 4) & 63;
          const size_t orow = (size_t)bb * 4096 + hh * 64 + wwp;
          outf[orow * 512 + col] = resid[orow * 512 + col] + v;
        }
    }
  } else {
#pragma unroll
    for (int nr = 0; nr < 4; ++nr) {
      const int col = n0 + wn * 64 + nr * 16 + lr;
      const float bc = bias[col];
#pragma unroll
      for (int mr = 0; mr < 8; ++mr)
#pragma unroll
        for (int e = 0; e < 4; ++e) {
          const int row = m0 + wm * 128 + mr * 16 + lg * 4 + e;
          outf[(size_t)row * 512 + col] = acc[mr][nr][e] + bc + resid[(size_t)row * 512 + col];
        }
    }
  }
}

// ---------------------------------------------------------------- 128x128 GEMM (qkv only)
// EPI 3: qkv -> Q (scaled) | K | VT[win][head][d][n], bf16
__global__ __launch_bounds__(256, 2)
void gemm128_qkv(const short* __restrict__ A, const short* __restrict__ BT,
                 const float* __restrict__ bias, short* __restrict__ outh) {
  constexpr int K = 512;
  __shared__ short As[128 * 32];
  __shared__ short Bs[128 * 32];
  const int tid = threadIdx.x, lane = tid & 63, wid = tid >> 6;
  const int lr = lane & 15, lg = lane >> 4;
  const int wm = wid >> 1, wn = wid & 1;
  const int m0 = blockIdx.y * 128, n0 = blockIdx.x * 128;
  const int srow = lane >> 2;
  const int scol = (lane & 3) * 8;
  f32x4 acc[4][4] = {};
  for (int kt = 0; kt < K; kt += 32) {
#pragma unroll
    for (int c = 0; c < 2; ++c) {
      const int chunk = wid * 2 + c;
      GLDS16(A  + (size_t)(m0 + chunk * 16 + srow) * K + kt + scol, As + chunk * 512);
      GLDS16(BT + (size_t)(n0 + chunk * 16 + srow) * K + kt + scol, Bs + chunk * 512);
    }
    __syncthreads();
    bf16x8 af[4], bf_[4];
#pragma unroll
    for (int t = 0; t < 4; ++t) af[t]  = *(const bf16x8*)(As + (wm * 64 + t * 16 + lr) * 32 + lg * 8);
#pragma unroll
    for (int t = 0; t < 4; ++t) bf_[t] = *(const bf16x8*)(Bs + (wn * 64 + t * 16 + lr) * 32 + lg * 8);
#pragma unroll
    for (int i = 0; i < 4; ++i)
#pragma unroll
      for (int j = 0; j < 4; ++j)
        acc[i][j] = __builtin_amdgcn_mfma_f32_16x16x32_bf16(af[i], bf_[j], acc[i][j], 0, 0, 0);
    __syncthreads();
  }
#pragma unroll
  for (int j = 0; j < 4; ++j) {
    const int col = n0 + wn * 64 + j * 16 + lr;
    const float bc = bias[col];
#pragma unroll
    for (int i = 0; i < 4; ++i)
#pragma unroll
      for (int e = 0; e < 4; ++e) {
        const int row = m0 + wm * 64 + i * 16 + lg * 4 + e;
        float v = acc[i][j][e] + bc;
        const int seg = col >> 9;
        if (seg == 0) {
          outh[(size_t)row * 512 + col] = f2bf(v * 0.17677669529663687f);  // Q * 1/sqrt(32)
        } else if (seg == 1) {
          outh[33554432 + (size_t)row * 512 + (col - 512)] = f2bf(v);      // K
        } else {
          const int cc = col - 1024;                                        // V^T
          outh[67108864 + (size_t)((row >> 6) * 16 + (cc >> 5)) * 2048 + (cc & 31) * 64 + (row & 63)] = f2bf(v);
        }
      }
  }
}

// ---------------------------------------------------------------- launch
extern "C" void kernel_launch(void* const* d_in, const int* in_sizes, int n_in,
                              void* d_out, int out_size, void* d_ws, size_t ws_size,
                              hipStream_t stream) {
  (void)in_sizes; (void)n_in; (void)out_size; (void)ws_size;
  const float* x      = (const float*)d_in[0];
  const float* g1     = (const float*)d_in[1];
  const float* b1     = (const float*)d_in[2];
  const float* qkv_w  = (const float*)d_in[3];
  const float* qkv_b  = (const float*)d_in[4];
  const float* proj_w = (const float*)d_in[5];
  const float* proj_b = (const float*)d_in[6];
  const float* rpb    = (const float*)d_in[7];
  const float* g2     = (const float*)d_in[8];
  const float* b2     = (const float*)d_in[9];
  const float* fc1_w  = (const float*)d_in[10];
  const float* fc1_b  = (const float*)d_in[11];
  const float* fc2_w  = (const float*)d_in[12];
  const float* fc2_b  = (const float*)d_in[13];
  float* out = (float*)d_out;
  char* ws = (char*)d_ws;

  short* WQKVT  = (short*)(ws);                 // [1536][512] bf16   1.5MB
  short* WPROJT = (short*)(ws + 1572864);       // [512][512]         0.5MB
  short* WFC1T  = (short*)(ws + 2097152);       // [2048][512]        2MB
  short* WFC2T  = (short*)(ws + 4194304);       // [512][2048]        2MB
  float* X2     = (float*)(ws + 6291456);       // [65536][512] fp32  134MB
  float* BIASF  = (float*)(ws + 6291456);       // 256KB alias (dead before proj)
  short* ATT    = (short*)(ws + 140509184);     // [65536][512] bf16  64MB (X2N reuse)
  short* XW     = (short*)(ws + 207618048);     // [65536][512] bf16  64MB
  short* QB     = (short*)(ws + 274726912);     // Q|K|VT 3x64MB
  short* H1     = XW;                           // [65536][2048] bf16 256MB over XW+QB (dead)
  short* X2N    = ATT;

  transpose_bf16<<<3072, 256, 0, stream>>>(qkv_w,  WQKVT, 512, 1536);
  transpose_bf16<<<1024, 256, 0, stream>>>(proj_w, WPROJT, 512, 512);
  transpose_bf16<<<4096, 256, 0, stream>>>(fc1_w,  WFC1T, 512, 2048);
  transpose_bf16<<<4096, 256, 0, stream>>>(fc2_w,  WFC2T, 2048, 512);
  bias_expand<<<256, 256, 0, stream>>>(rpb, BIASF);

  ln_kernel<1><<<16384, 256, 0, stream>>>(x, g1, b1, XW);
  gemm128_qkv<<<dim3(12, 512), 256, 0, stream>>>(XW, WQKVT, qkv_b, QB);
  attn_core<<<4096, 256, 0, stream>>>(QB, QB + 33554432, QB + 67108864, BIASF, ATT);
  // proj: A=ATT [65536][512], BT=WPROJT [512][512] -> X2 (window-reverse + x resid)
  gemm256<0, 512><<<512, 512, 0, stream>>>(ATT, WPROJT, proj_b, x, X2, nullptr);
  ln_kernel<0><<<16384, 256, 0, stream>>>(X2, g2, b2, X2N);
  // fc1 operand-swapped: A=W1T [2048][512], B=X2N [65536][512] -> H1[tok][h] bf16
  gemm256<1, 512><<<2048, 512, 0, stream>>>(WFC1T, X2N, fc1_b, nullptr, nullptr, H1);
  // fc2: A=H1 [65536][2048], BT=W2T [512][2048] -> out fp32 + bias + X2 residual
  gemm256<2, 2048><<<512, 512, 0, stream>>>(H1, WFC2T, fc2_b, X2, out, nullptr);
}